// Round 13
// baseline (168.114 us; speedup 1.0000x reference)
//
#include <hip/hip_runtime.h>
#include <hip/hip_bf16.h>

#define B_    32
#define T_    12
#define TM1   11
#define K_    16
#define DIM_  512
#define H0_   512
#define H1_   256
#define NROWS 5632
#define NBT   352
#define E_ELEMS (NBT*256*H1_)

typedef __bf16 bf16x8 __attribute__((ext_vector_type(8)));
typedef float  f32x16 __attribute__((ext_vector_type(16)));
typedef float  f32x4  __attribute__((ext_vector_type(4)));
typedef float  f32x2  __attribute__((ext_vector_type(2)));
typedef unsigned u32x4 __attribute__((ext_vector_type(4)));

#define OFRAG_OFF   0
#define W0FRAG_OFF  5767168
#define W1FRAG_OFF  (W0FRAG_OFF + 1048576)
#define UB_OFF      (W1FRAG_OFF + 262144)
#define VSW_OFF     (UB_OFF + 5767168)

__device__ __forceinline__ unsigned bf_rn(float f) {
    unsigned u = __float_as_uint(f);
    return (u + 0x7fffu + ((u >> 16) & 1u)) >> 16;
}
__device__ __forceinline__ unsigned pk_bf16(float lo, float hi) {
    return bf_rn(lo) | (bf_rn(hi) << 16);
}
__device__ __forceinline__ unsigned short f2bf(float f) {
    return (unsigned short)bf_rn(f);
}
__device__ __forceinline__ float bfu_lo(unsigned u) { return __uint_as_float(u << 16); }
__device__ __forceinline__ float bfu_hi(unsigned u) { return __uint_as_float(u & 0xffff0000u); }
// async global->LDS, 16B per lane, no VGPR round-trip
__device__ __forceinline__ void gl2lds16(const char* g, char* l) {
    __builtin_amdgcn_global_load_lds(
        (const __attribute__((address_space(1))) unsigned*)(const void*)g,
        (__attribute__((address_space(3))) unsigned*)(void*)l, 16, 0, 0);
}

// ---------------------------------------------------------------------------
// k_prep: merged W0/W1/O fragment repack (bf16, fragment-ordered).
// ---------------------------------------------------------------------------
__global__ __launch_bounds__(256) void k_prep(const float* __restrict__ W0,
                                              const float* __restrict__ W1,
                                              const float* __restrict__ O,
                                              char* __restrict__ ws)
{
    const int unit = blockIdx.x * 4 + (threadIdx.x >> 6);
    const int l = threadIdx.x & 63;
    if (unit < 1280) {
        const float* src; size_t dstoff; int stride;
        if (unit < 1024) {
            int half = unit >> 9, s = (unit >> 4) & 31, nt = unit & 15;
            int k = s*16 + (l >> 5)*8;
            int n = nt*32 + (l & 31);
            src = W0 + (size_t)(half*512 + k) * H0_ + n;
            stride = H0_;
            dstoff = W0FRAG_OFF + (((size_t)(half*32 + s)*16 + nt)*64 + l)*16;
        } else {
            int r = unit - 1024; int s = r >> 3, ct = r & 7;
            int k = s*16 + (l >> 5)*8;
            int n = ct*32 + (l & 31);
            src = W1 + (size_t)k * H1_ + n;
            stride = H1_;
            dstoff = W1FRAG_OFF + (((size_t)(s*8 + ct))*64 + l)*16;
        }
        float f[8];
        #pragma unroll
        for (int j = 0; j < 8; ++j) f[j] = src[(size_t)j * stride];
        u32x4 o = { pk_bf16(f[0],f[1]), pk_bf16(f[2],f[3]), pk_bf16(f[4],f[5]), pk_bf16(f[6],f[7]) };
        *(u32x4*)(ws + dstoff) = o;
    } else {
        const int u = unit - 1280;
        const int s = u / 176, mt = u % 176;
        const int row = mt*32 + (l & 31);
        const int b  = row / (TM1*K_);
        const int rem = row % (TM1*K_);
        const int t  = rem / K_;
        const int i  = rem % K_;
        const float* src = O + (((size_t)(b*T_ + t + 1)*K_ + i)*DIM_) + s*16 + (l >> 5)*8;
        float4 a = *(const float4*)src;
        float4 c = *(const float4*)(src + 4);
        u32x4 o = { pk_bf16(a.x,a.y), pk_bf16(a.z,a.w), pk_bf16(c.x,c.y), pk_bf16(c.z,c.w) };
        *(u32x4*)(ws + OFRAG_OFF + ((size_t)(s*176 + mt)*64 + l)*16) = o;
    }
}

// ---------------------------------------------------------------------------
// k_uv (unchanged)
// ---------------------------------------------------------------------------
__global__ __launch_bounds__(256) void k_uv(char* __restrict__ ws,
                                            const float* __restrict__ b0)
{
    const int mb = blockIdx.x;
    const int t  = threadIdx.x, l = t & 63;
    const int nb = blockIdx.y * 4 + (t >> 6);
    const int half = nb >> 3;
    const char* Ag = ws + OFRAG_OFF + ((size_t)(mb*2)*64 + l)*16;
    const char* Bg = ws + W0FRAG_OFF + (size_t)half*524288 + ((size_t)((nb&7)*2)*64 + l)*16;
    const size_t AS = 176*1024, BS = 16*1024;

    f32x16 acc[2][2];
    #pragma unroll
    for (int p = 0; p < 2; ++p)
        #pragma unroll
        for (int c = 0; c < 2; ++c)
            #pragma unroll
            for (int r = 0; r < 16; ++r) acc[p][c][r] = 0.f;

    u32x4 aA[2], bA[2], aB[2], bB[2];
    #pragma unroll
    for (int p = 0; p < 2; ++p) {
        aA[p] = *(const u32x4*)(Ag + 0*AS + p*1024);
        bA[p] = *(const u32x4*)(Bg + 0*BS + p*1024);
        aB[p] = *(const u32x4*)(Ag + 1*AS + p*1024);
        bB[p] = *(const u32x4*)(Bg + 1*BS + p*1024);
    }

    for (int ss = 0; ss < 32; ss += 2) {
        {
            union { u32x4 u[2]; bf16x8 b[2]; } af, bf;
            af.u[0]=aA[0]; af.u[1]=aA[1]; bf.u[0]=bA[0]; bf.u[1]=bA[1];
            if (ss + 2 < 32) {
                #pragma unroll
                for (int p = 0; p < 2; ++p) {
                    aA[p] = *(const u32x4*)(Ag + (size_t)(ss+2)*AS + p*1024);
                    bA[p] = *(const u32x4*)(Bg + (size_t)(ss+2)*BS + p*1024);
                }
            }
            acc[0][0] = __builtin_amdgcn_mfma_f32_32x32x16_bf16(af.b[0], bf.b[0], acc[0][0], 0,0,0);
            acc[0][1] = __builtin_amdgcn_mfma_f32_32x32x16_bf16(af.b[0], bf.b[1], acc[0][1], 0,0,0);
            acc[1][0] = __builtin_amdgcn_mfma_f32_32x32x16_bf16(af.b[1], bf.b[0], acc[1][0], 0,0,0);
            acc[1][1] = __builtin_amdgcn_mfma_f32_32x32x16_bf16(af.b[1], bf.b[1], acc[1][1], 0,0,0);
        }
        {
            union { u32x4 u[2]; bf16x8 b[2]; } af, bf;
            af.u[0]=aB[0]; af.u[1]=aB[1]; bf.u[0]=bB[0]; bf.u[1]=bB[1];
            if (ss + 3 < 32) {
                #pragma unroll
                for (int p = 0; p < 2; ++p) {
                    aB[p] = *(const u32x4*)(Ag + (size_t)(ss+3)*AS + p*1024);
                    bB[p] = *(const u32x4*)(Bg + (size_t)(ss+3)*BS + p*1024);
                }
            }
            acc[0][0] = __builtin_amdgcn_mfma_f32_32x32x16_bf16(af.b[0], bf.b[0], acc[0][0], 0,0,0);
            acc[0][1] = __builtin_amdgcn_mfma_f32_32x32x16_bf16(af.b[0], bf.b[1], acc[0][1], 0,0,0);
            acc[1][0] = __builtin_amdgcn_mfma_f32_32x32x16_bf16(af.b[1], bf.b[0], acc[1][0], 0,0,0);
            acc[1][1] = __builtin_amdgcn_mfma_f32_32x32x16_bf16(af.b[1], bf.b[1], acc[1][1], 0,0,0);
        }
    }

    #pragma unroll
    for (int p = 0; p < 2; ++p) {
        #pragma unroll
        for (int c = 0; c < 2; ++c) {
            const int col = (nb & 7)*64 + c*32 + (l & 31);
            const float bias = (half == 0) ? b0[col] : 0.f;
            #pragma unroll
            for (int r = 0; r < 16; ++r) {
                const int row = (r & 3) + 8*(r >> 2) + 4*(l >> 5);
                const int M = mb*64 + p*32 + row;
                const float v = acc[p][c][r] + bias;
                if (half == 0) {
                    *(unsigned short*)(ws + UB_OFF + ((size_t)M*512 + col)*2) = f2bf(v);
                } else {
                    const int bt = M >> 4, j = M & 15;
                    const int cc = col >> 3;
                    const int c2 = ((cc ^ (j & 7)) << 3) | (col & 7);
                    *(unsigned short*)(ws + VSW_OFF + ((size_t)(bt*16 + j)*512 + c2)*2) = f2bf(v);
                }
            }
        }
    }
}

// ---------------------------------------------------------------------------
// k_obj (unchanged)
// ---------------------------------------------------------------------------
__global__ __launch_bounds__(256) void k_obj(const float* __restrict__ O,
                                             float* __restrict__ out)
{
    __shared__ float red[16][16];
    __shared__ float fl[16];
    const int bt = blockIdx.x;
    const int b_ = bt / TM1, tt = bt % TM1;
    const int t  = threadIdx.x;
    const int i  = t >> 4, s = t & 15;
    const float* base = O + (((size_t)(b_ * T_ + tt + 1) * K_ + i) * DIM_) + s * 32;
    float sum = 0.f;
    #pragma unroll
    for (int q = 0; q < 8; ++q) {
        float4 v = *(const float4*)(base + q * 4);
        sum += v.x + v.y + v.z + v.w;
    }
    red[i][s] = sum;
    __syncthreads();
    if (t < 16) {
        float f = 0.f;
        #pragma unroll
        for (int s2 = 0; s2 < 16; ++s2) f += red[t][s2];
        fl[t] = fminf(fmaxf(f, 0.f), 1.f);
    }
    __syncthreads();
    const float val = fminf((float)(tt + 1) * fl[t >> 4] * fl[t & 15], 1.f);
    __builtin_nontemporal_store(val, out + (size_t)E_ELEMS + (size_t)bt * 256 + t);
}

// ---------------------------------------------------------------------------
// Shared k_e loop macros (v5)
// ---------------------------------------------------------------------------
#define WSTAGE(C, BUFOFF)                                                      \
    do {                                                                       \
        gl2lds16(Wsrc + (size_t)((C)*2 + 0)*8192, Wbuf + (BUFOFF) + wq*1024);  \
        gl2lds16(Wsrc + (size_t)((C)*2 + 1)*8192, Wbuf + (BUFOFF) + 4096 + wq*1024); \
    } while (0)

#define KSTEP_L(S, BUFOFF, ST)                                                 \
    do {                                                                       \
        const int vch_ = (((S)*2 + kc) ^ jlow_);                               \
        u32x4 vu_ = *(const u32x4*)(VsL + vch_*16);                            \
        u32x4 uu_ = *(const u32x4*)(UsL + (S)*32);                             \
        bf16x8 af_;                                                            \
        _Pragma("unroll")                                                      \
        for (int q_ = 0; q_ < 4; ++q_) {                                       \
            f32x2 u2_ = { bfu_lo(uu_[q_]), bfu_hi(uu_[q_]) };                  \
            f32x2 v2_ = { bfu_lo(vu_[q_]), bfu_hi(vu_[q_]) };                  \
            f32x2 s2_ = u2_ + v2_;                                             \
            af_[2*q_]   = (__bf16)fmaxf(s2_.x, 0.f);                           \
            af_[2*q_+1] = (__bf16)fmaxf(s2_.y, 0.f);                           \
        }                                                                      \
        union { u32x4 u[4]; bf16x8 b[4]; } wu_;                                \
        _Pragma("unroll")                                                      \
        for (int c_ = 0; c_ < 4; ++c_)                                         \
            wu_.u[c_] = *(const u32x4*)(WlL + (BUFOFF) + (ST)*4096 + c_*1024); \
        acc0 = __builtin_amdgcn_mfma_f32_32x32x16_bf16(af_, wu_.b[0], acc0, 0,0,0); \
        acc1 = __builtin_amdgcn_mfma_f32_32x32x16_bf16(af_, wu_.b[1], acc1, 0,0,0); \
        acc2 = __builtin_amdgcn_mfma_f32_32x32x16_bf16(af_, wu_.b[2], acc2, 0,0,0); \
        acc3 = __builtin_amdgcn_mfma_f32_32x32x16_bf16(af_, wu_.b[3], acc3, 0,0,0); \
    } while (0)

// ---------------------------------------------------------------------------
// k_e v5 (unchanged from R12, known-pass)
// ---------------------------------------------------------------------------
__global__ __launch_bounds__(256, 3) void k_e(const char* __restrict__ ws,
                                              const float* __restrict__ b1,
                                              float* __restrict__ out)
{
    __shared__ alignas(16) char lds[40960];
    char* Us   = lds;
    char* Vs   = lds + 8192;
    char* Wbuf = lds + 24576;

    const int bid = blockIdx.x;
    const int ch = bid & 1, ph = (bid >> 1) & 1, bt = bid >> 2;
    const int t = threadIdx.x, l = t & 63, wq = t >> 6;

    const char* Ug = ws + UB_OFF  + (size_t)(bt*16 + ph*8) * 1024;
    const char* Vg = ws + VSW_OFF + (size_t)bt * 16384;
    const char* Wsrc = ws + W1FRAG_OFF + (size_t)ch*4096 + (size_t)wq*1024 + (size_t)l*16;

    #pragma unroll
    for (int r = 0; r < 2; ++r) { int c = t + r*256; *(u32x4*)(Us + c*16) = *(const u32x4*)(Ug + c*16); }
    #pragma unroll
    for (int r = 0; r < 4; ++r) { int c = t + r*256; *(u32x4*)(Vs + c*16) = *(const u32x4*)(Vg + c*16); }

    WSTAGE(0, 0);
    __syncthreads();

    f32x16 acc0, acc1, acc2, acc3;
    #pragma unroll
    for (int r = 0; r < 16; ++r) { acc0[r] = 0.f; acc1[r] = 0.f; acc2[r] = 0.f; acc3[r] = 0.f; }

    const int jj    = l & 15;
    const int jlow_ = jj & 7;
    const int kc    = l >> 5;
    const int il    = wq*2 + ((l >> 4) & 1);
    const char* UsL = Us + il*1024 + kc*16;
    const char* VsL = Vs + jj*1024;
    const char* WlL = Wbuf + (size_t)l*16;

    for (int j = 0; j < 8; ++j) {
        const int c0 = j*2;
        if (c0 + 1 < 16) WSTAGE(c0+1, 8192);
        KSTEP_L(c0*2+0, 0, 0);
        KSTEP_L(c0*2+1, 0, 1);
        __syncthreads();
        if (c0 + 2 < 16) WSTAGE(c0+2, 0);
        KSTEP_L(c0*2+2, 8192, 0);
        KSTEP_L(c0*2+3, 8192, 1);
        __syncthreads();
    }

    const int colb = ch*128 + (l & 31);
    const int pr0  = ph*128 + wq*32 + 4*(l >> 5);
    float* ob = out + ((size_t)bt*256 + pr0)*256 + colb;
    #define EPI(ACC, CT)                                                       \
        do {                                                                   \
            const float bb_ = b1[colb + (CT)*32];                              \
            _Pragma("unroll")                                                  \
            for (int r_ = 0; r_ < 16; ++r_) {                                  \
                const int rr_ = (r_ & 3) + 8*(r_ >> 2);                        \
                __builtin_nontemporal_store(fmaxf(ACC[r_] + bb_, 0.f),         \
                    ob + (size_t)rr_*256 + (CT)*32);                           \
            }                                                                  \
        } while (0)
    EPI(acc0, 0);
    EPI(acc1, 1);
    EPI(acc2, 2);
    EPI(acc3, 3);
    #undef EPI
}

// ---------------------------------------------------------------------------
// DIAG k_e_d0r: exact v5 loop, REP=4 back-to-back, NO out stores. acc carried
// across reps (keeps all MFMAs live); checksum -> dead Ofrag scrap.
// Readout: if its dur tops the table, compute-only C = dur/4. If absent from
// top-5 (fills ~54-62 us), then 4C < ~57 -> C < ~15 -> stores guilty.
// ---------------------------------------------------------------------------
__global__ __launch_bounds__(256, 3) void k_e_d0r(const char* __restrict__ ws,
                                                  char* __restrict__ scrap)
{
    __shared__ alignas(16) char lds[40960];
    char* Us   = lds;
    char* Vs   = lds + 8192;
    char* Wbuf = lds + 24576;

    const int bid = blockIdx.x;
    const int ch = bid & 1, ph = (bid >> 1) & 1, bt = bid >> 2;
    const int t = threadIdx.x, l = t & 63, wq = t >> 6;

    const char* Ug = ws + UB_OFF  + (size_t)(bt*16 + ph*8) * 1024;
    const char* Vg = ws + VSW_OFF + (size_t)bt * 16384;
    const char* Wsrc = ws + W1FRAG_OFF + (size_t)ch*4096 + (size_t)wq*1024 + (size_t)l*16;

    #pragma unroll
    for (int r = 0; r < 2; ++r) { int c = t + r*256; *(u32x4*)(Us + c*16) = *(const u32x4*)(Ug + c*16); }
    #pragma unroll
    for (int r = 0; r < 4; ++r) { int c = t + r*256; *(u32x4*)(Vs + c*16) = *(const u32x4*)(Vg + c*16); }

    WSTAGE(0, 0);
    __syncthreads();

    f32x16 acc0, acc1, acc2, acc3;
    #pragma unroll
    for (int r = 0; r < 16; ++r) { acc0[r] = 0.f; acc1[r] = 0.f; acc2[r] = 0.f; acc3[r] = 0.f; }

    const int jj    = l & 15;
    const int jlow_ = jj & 7;
    const int kc    = l >> 5;
    const int il    = wq*2 + ((l >> 4) & 1);
    const char* UsL = Us + il*1024 + kc*16;
    const char* VsL = Vs + jj*1024;
    const char* WlL = Wbuf + (size_t)l*16;

    for (int rep = 0; rep < 4; ++rep) {
        for (int j = 0; j < 8; ++j) {
            const int c0 = j*2;
            if (c0 + 1 < 16) WSTAGE(c0+1, 8192);
            KSTEP_L(c0*2+0, 0, 0);
            KSTEP_L(c0*2+1, 0, 1);
            __syncthreads();
            if (c0 + 2 < 16) WSTAGE(c0+2, 0);
            KSTEP_L(c0*2+2, 8192, 0);
            KSTEP_L(c0*2+3, 8192, 1);
            __syncthreads();
        }
        if (rep < 3) {
            WSTAGE(0, 0);         // re-stage chunk 0 for the next rep
            __syncthreads();
        }
    }

    float sum = 0.f;
    #pragma unroll
    for (int r = 0; r < 16; ++r) sum += acc0[r] + acc1[r] + acc2[r] + acc3[r];
    *(float*)(scrap + ((size_t)bid*256 + t)*4) = sum;
}

// ---------------------------------------------------------------------------
extern "C" void kernel_launch(void* const* d_in, const int* in_sizes, int n_in,
                              void* d_out, int out_size, void* d_ws, size_t ws_size,
                              hipStream_t stream) {
    const float* O  = (const float*)d_in[0];
    const float* W0 = (const float*)d_in[1];
    const float* b0 = (const float*)d_in[2];
    const float* W1 = (const float*)d_in[3];
    const float* b1 = (const float*)d_in[4];
    float* out = (float*)d_out;
    char* ws = (char*)d_ws;

    k_prep<<<1728, 256, 0, stream>>>(W0, W1, O, ws);
    dim3 guv(88, 4);
    k_uv<<<guv, 256, 0, stream>>>(ws, b0);
    k_obj<<<NBT, 256, 0, stream>>>(O, out);

    // DIAG (one round only): compute-only x4, writes to dead Ofrag scrap
    k_e_d0r<<<NBT * 4, 256, 0, stream>>>(ws, ws + OFRAG_OFF);

    k_e<<<NBT * 4, 256, 0, stream>>>(ws, b1, out);
}

// Round 14
// 63.050 us; speedup vs baseline: 2.6664x; 2.6664x over previous
//
#include <hip/hip_runtime.h>
#include <hip/hip_bf16.h>

#define B_    32
#define T_    12
#define TM1   11
#define K_    16
#define DIM_  512
#define H0_   512
#define H1_   256
#define NROWS 5632
#define NBT   352
#define E_ELEMS (NBT*256*H1_)

typedef __bf16 bf16x8 __attribute__((ext_vector_type(8)));
typedef float  f32x16 __attribute__((ext_vector_type(16)));
typedef float  f32x4  __attribute__((ext_vector_type(4)));
typedef float  f32x2  __attribute__((ext_vector_type(2)));
typedef unsigned u32x4 __attribute__((ext_vector_type(4)));

#define OFRAG_OFF   0
#define W0FRAG_OFF  5767168
#define W1FRAG_OFF  (W0FRAG_OFF + 1048576)
#define UB_OFF      (W1FRAG_OFF + 262144)
#define VSW_OFF     (UB_OFF + 5767168)

__device__ __forceinline__ unsigned bf_rn(float f) {
    unsigned u = __float_as_uint(f);
    return (u + 0x7fffu + ((u >> 16) & 1u)) >> 16;
}
__device__ __forceinline__ unsigned pk_bf16(float lo, float hi) {
    return bf_rn(lo) | (bf_rn(hi) << 16);
}
__device__ __forceinline__ unsigned short f2bf(float f) {
    return (unsigned short)bf_rn(f);
}
__device__ __forceinline__ float bfu_lo(unsigned u) { return __uint_as_float(u << 16); }
__device__ __forceinline__ float bfu_hi(unsigned u) { return __uint_as_float(u & 0xffff0000u); }
// async global->LDS, 16B per lane, no VGPR round-trip
__device__ __forceinline__ void gl2lds16(const char* g, char* l) {
    __builtin_amdgcn_global_load_lds(
        (const __attribute__((address_space(1))) unsigned*)(const void*)g,
        (__attribute__((address_space(3))) unsigned*)(void*)l, 16, 0, 0);
}

// ---------------------------------------------------------------------------
// k_prep: merged W0/W1/O fragment repack (bf16, fragment-ordered).
// ---------------------------------------------------------------------------
__global__ __launch_bounds__(256) void k_prep(const float* __restrict__ W0,
                                              const float* __restrict__ W1,
                                              const float* __restrict__ O,
                                              char* __restrict__ ws)
{
    const int unit = blockIdx.x * 4 + (threadIdx.x >> 6);
    const int l = threadIdx.x & 63;
    if (unit < 1280) {
        const float* src; size_t dstoff; int stride;
        if (unit < 1024) {
            int half = unit >> 9, s = (unit >> 4) & 31, nt = unit & 15;
            int k = s*16 + (l >> 5)*8;
            int n = nt*32 + (l & 31);
            src = W0 + (size_t)(half*512 + k) * H0_ + n;
            stride = H0_;
            dstoff = W0FRAG_OFF + (((size_t)(half*32 + s)*16 + nt)*64 + l)*16;
        } else {
            int r = unit - 1024; int s = r >> 3, ct = r & 7;
            int k = s*16 + (l >> 5)*8;
            int n = ct*32 + (l & 31);
            src = W1 + (size_t)k * H1_ + n;
            stride = H1_;
            dstoff = W1FRAG_OFF + (((size_t)(s*8 + ct))*64 + l)*16;
        }
        float f[8];
        #pragma unroll
        for (int j = 0; j < 8; ++j) f[j] = src[(size_t)j * stride];
        u32x4 o = { pk_bf16(f[0],f[1]), pk_bf16(f[2],f[3]), pk_bf16(f[4],f[5]), pk_bf16(f[6],f[7]) };
        *(u32x4*)(ws + dstoff) = o;
    } else {
        const int u = unit - 1280;
        const int s = u / 176, mt = u % 176;
        const int row = mt*32 + (l & 31);
        const int b  = row / (TM1*K_);
        const int rem = row % (TM1*K_);
        const int t  = rem / K_;
        const int i  = rem % K_;
        const float* src = O + (((size_t)(b*T_ + t + 1)*K_ + i)*DIM_) + s*16 + (l >> 5)*8;
        float4 a = *(const float4*)src;
        float4 c = *(const float4*)(src + 4);
        u32x4 o = { pk_bf16(a.x,a.y), pk_bf16(a.z,a.w), pk_bf16(c.x,c.y), pk_bf16(c.z,c.w) };
        *(u32x4*)(ws + OFRAG_OFF + ((size_t)(s*176 + mt)*64 + l)*16) = o;
    }
}

// ---------------------------------------------------------------------------
// k_uv (unchanged): block mb covers bts 4mb..4mb+3; XCD(mb) = mb%8 since the
// 88-wide x-dim is 0 mod 8 (y adds 88*y ≡ 0). k_e's swizzle matches this.
// ---------------------------------------------------------------------------
__global__ __launch_bounds__(256) void k_uv(char* __restrict__ ws,
                                            const float* __restrict__ b0)
{
    const int mb = blockIdx.x;
    const int t  = threadIdx.x, l = t & 63;
    const int nb = blockIdx.y * 4 + (t >> 6);
    const int half = nb >> 3;
    const char* Ag = ws + OFRAG_OFF + ((size_t)(mb*2)*64 + l)*16;
    const char* Bg = ws + W0FRAG_OFF + (size_t)half*524288 + ((size_t)((nb&7)*2)*64 + l)*16;
    const size_t AS = 176*1024, BS = 16*1024;

    f32x16 acc[2][2];
    #pragma unroll
    for (int p = 0; p < 2; ++p)
        #pragma unroll
        for (int c = 0; c < 2; ++c)
            #pragma unroll
            for (int r = 0; r < 16; ++r) acc[p][c][r] = 0.f;

    u32x4 aA[2], bA[2], aB[2], bB[2];
    #pragma unroll
    for (int p = 0; p < 2; ++p) {
        aA[p] = *(const u32x4*)(Ag + 0*AS + p*1024);
        bA[p] = *(const u32x4*)(Bg + 0*BS + p*1024);
        aB[p] = *(const u32x4*)(Ag + 1*AS + p*1024);
        bB[p] = *(const u32x4*)(Bg + 1*BS + p*1024);
    }

    for (int ss = 0; ss < 32; ss += 2) {
        {
            union { u32x4 u[2]; bf16x8 b[2]; } af, bf;
            af.u[0]=aA[0]; af.u[1]=aA[1]; bf.u[0]=bA[0]; bf.u[1]=bA[1];
            if (ss + 2 < 32) {
                #pragma unroll
                for (int p = 0; p < 2; ++p) {
                    aA[p] = *(const u32x4*)(Ag + (size_t)(ss+2)*AS + p*1024);
                    bA[p] = *(const u32x4*)(Bg + (size_t)(ss+2)*BS + p*1024);
                }
            }
            acc[0][0] = __builtin_amdgcn_mfma_f32_32x32x16_bf16(af.b[0], bf.b[0], acc[0][0], 0,0,0);
            acc[0][1] = __builtin_amdgcn_mfma_f32_32x32x16_bf16(af.b[0], bf.b[1], acc[0][1], 0,0,0);
            acc[1][0] = __builtin_amdgcn_mfma_f32_32x32x16_bf16(af.b[1], bf.b[0], acc[1][0], 0,0,0);
            acc[1][1] = __builtin_amdgcn_mfma_f32_32x32x16_bf16(af.b[1], bf.b[1], acc[1][1], 0,0,0);
        }
        {
            union { u32x4 u[2]; bf16x8 b[2]; } af, bf;
            af.u[0]=aB[0]; af.u[1]=aB[1]; bf.u[0]=bB[0]; bf.u[1]=bB[1];
            if (ss + 3 < 32) {
                #pragma unroll
                for (int p = 0; p < 2; ++p) {
                    aB[p] = *(const u32x4*)(Ag + (size_t)(ss+3)*AS + p*1024);
                    bB[p] = *(const u32x4*)(Bg + (size_t)(ss+3)*BS + p*1024);
                }
            }
            acc[0][0] = __builtin_amdgcn_mfma_f32_32x32x16_bf16(af.b[0], bf.b[0], acc[0][0], 0,0,0);
            acc[0][1] = __builtin_amdgcn_mfma_f32_32x32x16_bf16(af.b[0], bf.b[1], acc[0][1], 0,0,0);
            acc[1][0] = __builtin_amdgcn_mfma_f32_32x32x16_bf16(af.b[1], bf.b[0], acc[1][0], 0,0,0);
            acc[1][1] = __builtin_amdgcn_mfma_f32_32x32x16_bf16(af.b[1], bf.b[1], acc[1][1], 0,0,0);
        }
    }

    #pragma unroll
    for (int p = 0; p < 2; ++p) {
        #pragma unroll
        for (int c = 0; c < 2; ++c) {
            const int col = (nb & 7)*64 + c*32 + (l & 31);
            const float bias = (half == 0) ? b0[col] : 0.f;
            #pragma unroll
            for (int r = 0; r < 16; ++r) {
                const int row = (r & 3) + 8*(r >> 2) + 4*(l >> 5);
                const int M = mb*64 + p*32 + row;
                const float v = acc[p][c][r] + bias;
                if (half == 0) {
                    *(unsigned short*)(ws + UB_OFF + ((size_t)M*512 + col)*2) = f2bf(v);
                } else {
                    const int bt = M >> 4, j = M & 15;
                    const int cc = col >> 3;
                    const int c2 = ((cc ^ (j & 7)) << 3) | (col & 7);
                    *(unsigned short*)(ws + VSW_OFF + ((size_t)(bt*16 + j)*512 + c2)*2) = f2bf(v);
                }
            }
        }
    }
}

// ---------------------------------------------------------------------------
// k_obj (unchanged; now launched BEFORE k_uv so its 12.6MB O sweep doesn't
// evict freshly-written Ub/Vsw from the per-XCD L2s)
// ---------------------------------------------------------------------------
__global__ __launch_bounds__(256) void k_obj(const float* __restrict__ O,
                                             float* __restrict__ out)
{
    __shared__ float red[16][16];
    __shared__ float fl[16];
    const int bt = blockIdx.x;
    const int b_ = bt / TM1, tt = bt % TM1;
    const int t  = threadIdx.x;
    const int i  = t >> 4, s = t & 15;
    const float* base = O + (((size_t)(b_ * T_ + tt + 1) * K_ + i) * DIM_) + s * 32;
    float sum = 0.f;
    #pragma unroll
    for (int q = 0; q < 8; ++q) {
        float4 v = *(const float4*)(base + q * 4);
        sum += v.x + v.y + v.z + v.w;
    }
    red[i][s] = sum;
    __syncthreads();
    if (t < 16) {
        float f = 0.f;
        #pragma unroll
        for (int s2 = 0; s2 < 16; ++s2) f += red[t][s2];
        fl[t] = fminf(fmaxf(f, 0.f), 1.f);
    }
    __syncthreads();
    const float val = fminf((float)(tt + 1) * fl[t >> 4] * fl[t & 15], 1.f);
    __builtin_nontemporal_store(val, out + (size_t)E_ELEMS + (size_t)bt * 256 + t);
}

// ---------------------------------------------------------------------------
// Shared k_e loop macros (v5)
// ---------------------------------------------------------------------------
#define WSTAGE(C, BUFOFF)                                                      \
    do {                                                                       \
        gl2lds16(Wsrc + (size_t)((C)*2 + 0)*8192, Wbuf + (BUFOFF) + wq*1024);  \
        gl2lds16(Wsrc + (size_t)((C)*2 + 1)*8192, Wbuf + (BUFOFF) + 4096 + wq*1024); \
    } while (0)

#define KSTEP_L(S, BUFOFF, ST)                                                 \
    do {                                                                       \
        const int vch_ = (((S)*2 + kc) ^ jlow_);                               \
        u32x4 vu_ = *(const u32x4*)(VsL + vch_*16);                            \
        u32x4 uu_ = *(const u32x4*)(UsL + (S)*32);                             \
        bf16x8 af_;                                                            \
        _Pragma("unroll")                                                      \
        for (int q_ = 0; q_ < 4; ++q_) {                                       \
            f32x2 u2_ = { bfu_lo(uu_[q_]), bfu_hi(uu_[q_]) };                  \
            f32x2 v2_ = { bfu_lo(vu_[q_]), bfu_hi(vu_[q_]) };                  \
            f32x2 s2_ = u2_ + v2_;                                             \
            af_[2*q_]   = (__bf16)fmaxf(s2_.x, 0.f);                           \
            af_[2*q_+1] = (__bf16)fmaxf(s2_.y, 0.f);                           \
        }                                                                      \
        union { u32x4 u[4]; bf16x8 b[4]; } wu_;                                \
        _Pragma("unroll")                                                      \
        for (int c_ = 0; c_ < 4; ++c_)                                         \
            wu_.u[c_] = *(const u32x4*)(WlL + (BUFOFF) + (ST)*4096 + c_*1024); \
        acc0 = __builtin_amdgcn_mfma_f32_32x32x16_bf16(af_, wu_.b[0], acc0, 0,0,0); \
        acc1 = __builtin_amdgcn_mfma_f32_32x32x16_bf16(af_, wu_.b[1], acc1, 0,0,0); \
        acc2 = __builtin_amdgcn_mfma_f32_32x32x16_bf16(af_, wu_.b[2], acc2, 0,0,0); \
        acc3 = __builtin_amdgcn_mfma_f32_32x32x16_bf16(af_, wu_.b[3], acc3, 0,0,0); \
    } while (0)

// ---------------------------------------------------------------------------
// k_e v6: v5 loop/epilogue, but blockIdx swizzled so each (bt,sub) block lands
// on the XCD whose L2 holds bt's Ub/Vsw (written by k_uv block mb=bt>>2,
// XCD=mb%8). Mapping: lane8=bid&7 (XCD under round-robin dispatch), and
// bt = q*32 + lane8*4 + (r>>2) makes (bt>>2)%8 == lane8. Bijective: 352=11*32.
// ---------------------------------------------------------------------------
__global__ __launch_bounds__(256, 3) void k_e(const char* __restrict__ ws,
                                              const float* __restrict__ b1,
                                              float* __restrict__ out)
{
    __shared__ alignas(16) char lds[40960];
    char* Us   = lds;
    char* Vs   = lds + 8192;
    char* Wbuf = lds + 24576;

    const int bid0 = blockIdx.x;
    const int lane8 = bid0 & 7;
    const int g = bid0 >> 3;          // 0..175
    const int q = g >> 4;             // 0..10
    const int r = g & 15;             // 0..15
    const int bt  = q*32 + lane8*4 + (r >> 2);
    const int sub = r & 3;
    const int ch = sub & 1, ph = sub >> 1;
    const int t = threadIdx.x, l = t & 63, wq = t >> 6;

    const char* Ug = ws + UB_OFF  + (size_t)(bt*16 + ph*8) * 1024;
    const char* Vg = ws + VSW_OFF + (size_t)bt * 16384;
    const char* Wsrc = ws + W1FRAG_OFF + (size_t)ch*4096 + (size_t)wq*1024 + (size_t)l*16;

    #pragma unroll
    for (int r2 = 0; r2 < 2; ++r2) { int c = t + r2*256; *(u32x4*)(Us + c*16) = *(const u32x4*)(Ug + c*16); }
    #pragma unroll
    for (int r2 = 0; r2 < 4; ++r2) { int c = t + r2*256; *(u32x4*)(Vs + c*16) = *(const u32x4*)(Vg + c*16); }

    WSTAGE(0, 0);
    __syncthreads();

    f32x16 acc0, acc1, acc2, acc3;
    #pragma unroll
    for (int r2 = 0; r2 < 16; ++r2) { acc0[r2] = 0.f; acc1[r2] = 0.f; acc2[r2] = 0.f; acc3[r2] = 0.f; }

    const int jj    = l & 15;
    const int jlow_ = jj & 7;
    const int kc    = l >> 5;
    const int il    = wq*2 + ((l >> 4) & 1);
    const char* UsL = Us + il*1024 + kc*16;
    const char* VsL = Vs + jj*1024;
    const char* WlL = Wbuf + (size_t)l*16;

    for (int j = 0; j < 8; ++j) {
        const int c0 = j*2;
        if (c0 + 1 < 16) WSTAGE(c0+1, 8192);
        KSTEP_L(c0*2+0, 0, 0);
        KSTEP_L(c0*2+1, 0, 1);
        __syncthreads();
        if (c0 + 2 < 16) WSTAGE(c0+2, 0);
        KSTEP_L(c0*2+2, 8192, 0);
        KSTEP_L(c0*2+3, 8192, 1);
        __syncthreads();
    }

    const int colb = ch*128 + (l & 31);
    const int pr0  = ph*128 + wq*32 + 4*(l >> 5);
    float* ob = out + ((size_t)bt*256 + pr0)*256 + colb;
    #define EPI(ACC, CT)                                                       \
        do {                                                                   \
            const float bb_ = b1[colb + (CT)*32];                              \
            _Pragma("unroll")                                                  \
            for (int r_ = 0; r_ < 16; ++r_) {                                  \
                const int rr_ = (r_ & 3) + 8*(r_ >> 2);                        \
                __builtin_nontemporal_store(fmaxf(ACC[r_] + bb_, 0.f),         \
                    ob + (size_t)rr_*256 + (CT)*32);                           \
            }                                                                  \
        } while (0)
    EPI(acc0, 0);
    EPI(acc1, 1);
    EPI(acc2, 2);
    EPI(acc3, 3);
    #undef EPI
}

// ---------------------------------------------------------------------------
extern "C" void kernel_launch(void* const* d_in, const int* in_sizes, int n_in,
                              void* d_out, int out_size, void* d_ws, size_t ws_size,
                              hipStream_t stream) {
    const float* O  = (const float*)d_in[0];
    const float* W0 = (const float*)d_in[1];
    const float* b0 = (const float*)d_in[2];
    const float* W1 = (const float*)d_in[3];
    const float* b1 = (const float*)d_in[4];
    float* out = (float*)d_out;
    char* ws = (char*)d_ws;

    k_prep<<<1728, 256, 0, stream>>>(W0, W1, O, ws);
    k_obj<<<NBT, 256, 0, stream>>>(O, out);          // before k_uv: keep L2 fresh for k_e
    dim3 guv(88, 4);
    k_uv<<<guv, 256, 0, stream>>>(ws, b0);
    k_e<<<NBT * 4, 256, 0, stream>>>(ws, b1, out);
}